// Round 6
// baseline (342.025 us; speedup 1.0000x reference)
//
#include <hip/hip_runtime.h>
#include <hip/hip_bf16.h>

// BinTreeNetwork (ALL TENSORS FP32):
//   out[B, o] = out0[o] + out_bias[o]
//             + sum_{i=0}^{20} res_i[B mod 2^{i+1}, :] . out_layers[i][o, :]
//
// Main path (ws >= 24 MB):
//   k_dots:  36 dot products (x . rows of inL/inR/outL0) -> ws dots[36]
//   k_paths: ALL res-table rows, levels 0..16, fully parallel (affine 2x2
//            chain per row from the level-0 seed).
//   k_c16f:  C16[m][o] = (dots[4+o]+outB[o]) + sum_{i=0..16} res_i[...].outL[i]
//            XCD-swizzled so XCD g WRITES rows [g*2^14,(g+1)*2^14).
//   k_final_c16: out[B] = C16[B&0x1FFFF] + chains 17..20.
//            XCD-swizzled so XCD g READS only C16 rows [g*2^14,(g+1)*2^14)
//            (2 MB, L2-resident; the 16x row re-reads become L2 hits instead
//            of L3/HBM traffic competing with the 268 MB nt write stream).
//
// ws layout (fp32 elements):
//   [0, 2^19-4)  res tables, level i at (1<<(i+2))-4
//   P0 = 1<<19: +1664 dots[36]
//     (legacy fallback also uses: +0 base, +32 outLf, +1376 tLf, +1460 tRf,
//      +1544 tLbf, +1586 tRbf, +2048 C7)
//   C14OFF = 1<<20 floats: C14 (fallback, ws >= 8 MB)
//   C16OFF = 1<<21 floats: C16 (main, ws >= 24 MB)

#define P0 (1u << 19)
#define C14OFF (1u << 20)
#define C16OFF (1u << 21)

typedef float floatx4 __attribute__((ext_vector_type(4)));

// ---------------- K0: 36 dot products row.x, one block each -----------------
__global__ __launch_bounds__(1024) void k_dots(
    const float* __restrict__ x,
    const float* __restrict__ inL,
    const float* __restrict__ inR,
    const float* __restrict__ outL0,
    float* __restrict__ ws)
{
    __shared__ float red[16];
    const int d = blockIdx.x;
    const int tid = threadIdx.x;
    const float* row =
        (d < 2) ? inL + d * 4096 :
        (d < 4) ? inR + (d - 2) * 4096 :
                  outL0 + (d - 4) * 4096;
    floatx4 a = ((const floatx4*)row)[tid];
    floatx4 b = ((const floatx4*)x)[tid];
    float s = a.x * b.x + a.y * b.y + a.z * b.z + a.w * b.w;
    #pragma unroll
    for (int off = 32; off; off >>= 1) s += __shfl_down(s, off, 64);
    if ((tid & 63) == 0) red[tid >> 6] = s;
    __syncthreads();
    if (tid < 16) {
        float v = red[tid];
        #pragma unroll
        for (int off = 8; off; off >>= 1) v += __shfl_down(v, off, 16);
        if (tid == 0) ws[P0 + 1664 + d] = v;
    }
}

// ---------------- K1 (main): all res-table rows in parallel ------------------
__global__ __launch_bounds__(256) void k_paths(
    const float* __restrict__ treeL,
    const float* __restrict__ treeR,
    const float* __restrict__ treeLb,
    const float* __restrict__ treeRb,
    const float* __restrict__ inLb,
    const float* __restrict__ inRb,
    float* __restrict__ ws)
{
    const unsigned t = blockIdx.x * 256u + threadIdx.x;
    const float* dots = ws + P0 + 1664;

    if (t < 2) {   // level-0 seed rows
        ws[t * 2 + 0] = dots[t]     + inLb[t];
        ws[t * 2 + 1] = dots[2 + t] + inRb[t];
    }
    if (t >= (1u << 18) - 4) return;

    const unsigned u = t + 4u;
    const int i = (31 - __clz(u)) - 1;          // level, in [1,16]
    unsigned m = u - (1u << (i + 1));           // row within level i
    unsigned sbits = 0;
    for (int l = i; l >= 1; --l) {              // descend, record selects
        sbits |= ((m >> (l - 1)) & 1u) << l;
        m = ((m >> l) << (l - 1)) | (m & ((1u << (l - 1)) - 1u));
    }
    // m in {0,1}: seed
    float v0 = dots[m]     + inLb[m];
    float v1 = dots[2 + m] + inRb[m];
    for (int l = 1; l <= i; ++l) {              // ascend, apply affine chain
        const int s = (sbits >> l) & 1;
        const float* W  = (s ? treeR  : treeL)  + (l - 1) * 4;
        const float* bb = (s ? treeRb : treeLb) + (l - 1) * 2;
        const float n0 = W[0] * v0 + W[1] * v1 + bb[0];
        const float n1 = W[2] * v0 + W[3] * v1 + bb[1];
        v0 = n0; v1 = n1;
    }
    // level i row m lives at float offset (1<<(i+2))-4 + 2m == 2t+4
    ws[2 * t + 4] = v0;
    ws[2 * t + 5] = v1;
}

// ---------------- K2 (main): fold base + levels 0..16 into C16[2^17][32] ----
// XCD-swizzled writer: hw block hb (XCD = hb&7) -> virtual block
// vblk = (hb&7)*64 + (hb>>3), so XCD g writes rows [g*2^14,(g+1)*2^14).
__global__ __launch_bounds__(256) void k_c16f(
    const float* __restrict__ outLs,
    const float* __restrict__ outB,
    float* __restrict__ ws)
{
    const unsigned hb = blockIdx.x;                       // [0,512)
    const unsigned vblk = (hb & 7u) * 64u + (hb >> 3);    // bijection on [0,512)
    const unsigned m = vblk * 256u + threadIdx.x;         // 2^17 rows
    const float* dots = ws + P0 + 1664;

    float acc[32];
    #pragma unroll
    for (int o = 0; o < 32; ++o) acc[o] = dots[4 + o] + outB[o];
    #pragma unroll
    for (int i = 0; i <= 16; ++i) {
        const float2 v = *(const float2*)(ws + ((1u << (i + 2)) - 4)
                                             + (m & ((2u << i) - 1)) * 2);
        const float* cf = outLs + i * 64;
        #pragma unroll
        for (int o = 0; o < 32; ++o)
            acc[o] += v.x * cf[o * 2] + v.y * cf[o * 2 + 1];
    }
    floatx4* dst = (floatx4*)(ws + C16OFF + (size_t)m * 32);
    #pragma unroll
    for (int q = 0; q < 8; ++q)
        dst[q] = (floatx4){acc[q * 4 + 0], acc[q * 4 + 1],
                           acc[q * 4 + 2], acc[q * 4 + 3]};
}

// ---------------- K3 (main): final gather-sum --------------------------------
// Per leaf: C16 row + register chains 17..20 (~290 FMA/leaf).
// XCD-swizzled reader: hw block b -> virtual block v with row-group
// (v&511) in [g*64,(g+1)*64) for XCD g = b&7; all 16 replicas of a row-chunk
// land on the same XCD -> C16 reads are 2 MB/XCD, L2-resident.
// Store path: LDS transpose (XOR-swizzled, conflict-free) -> contiguous
// 1 KiB-per-instruction nontemporal stores, 1.0x write amplification.
__global__ __launch_bounds__(256) void k_final_c16(
    const float* __restrict__ ws,
    const float* __restrict__ outLs,
    const float* __restrict__ treeL,
    const float* __restrict__ treeR,
    const float* __restrict__ treeLb,
    const float* __restrict__ treeRb,
    float* __restrict__ out)
{
    __shared__ floatx4 st[256 * 8];   // 32 KiB
    const int tid = threadIdx.x;
    const unsigned b = blockIdx.x;                 // [0,8192)
    const unsigned g = b & 7u, j = b >> 3;
    const unsigned v = (j >> 6) * 512u + g * 64u + (j & 63u);  // bijection
    const unsigned B = v * 256u + tid;
    const float* C16 = ws + C16OFF;

    float acc[32];
    {   // C16 row (contiguous 128 B, 16B-aligned; L2-resident slice)
        const floatx4* c4 = (const floatx4*)(C16 + (size_t)(B & 0x1FFFFu) * 32);
        #pragma unroll
        for (int q = 0; q < 8; ++q) {
            floatx4 vq = c4[q];
            acc[q * 4 + 0] = vq.x; acc[q * 4 + 1] = vq.y;
            acc[q * 4 + 2] = vq.z; acc[q * 4 + 3] = vq.w;
        }
    }

    // levels 17..20: two register chains from the two level-16 ancestor rows
    {
        const unsigned Blo = B & 0xFFFFu;
        const float* r16 = ws + ((1u << 18) - 4);
        float2 vA = *(const float2*)(r16 + Blo * 2);
        float2 vC = *(const float2*)(r16 + (Blo + 65536u) * 2);
        float A0 = vA.x, A1 = vA.y;   // MSB=0 chain
        float c0 = vC.x, c1 = vC.y;   // MSB=1 chain
        #pragma unroll
        for (int l = 17; l <= 20; ++l) {
            const int s = (B >> (l - 1)) & 1;
            const float* WL = treeL  + (l - 1) * 4;   // uniform -> scalar loads
            const float* WR = treeR  + (l - 1) * 4;
            const float* bL = treeLb + (l - 1) * 2;
            const float* bR = treeRb + (l - 1) * 2;
            const float w00 = s ? WR[0] : WL[0], w01 = s ? WR[1] : WL[1];
            const float w10 = s ? WR[2] : WL[2], w11 = s ? WR[3] : WL[3];
            const float b0  = s ? bR[0] : bL[0], b1  = s ? bR[1] : bL[1];
            const float nA0 = w00 * A0 + w01 * A1 + b0;
            const float nA1 = w10 * A0 + w11 * A1 + b1;
            const float nc0 = w00 * c0 + w01 * c1 + b0;
            const float nc1 = w10 * c0 + w11 * c1 + b1;
            A0 = nA0; A1 = nA1; c0 = nc0; c1 = nc1;
            const int pick = (B >> l) & 1;
            const float q0 = pick ? c0 : A0, q1 = pick ? c1 : A1;
            const float* cf = outLs + l * 64;
            #pragma unroll
            for (int o = 0; o < 32; ++o)
                acc[o] += q0 * cf[o * 2] + q1 * cf[o * 2 + 1];
        }
    }

    // ---- transpose through LDS, then fully-coalesced 1 KiB/instr nt stores --
    #pragma unroll
    for (int q = 0; q < 8; ++q) {
        st[tid * 8 + (q ^ (tid & 7))] =
            (floatx4){acc[q * 4 + 0], acc[q * 4 + 1],
                      acc[q * 4 + 2], acc[q * 4 + 3]};
    }
    __syncthreads();
    {
        const int w = tid >> 6, lane = tid & 63;
        const int x = (lane & 7) ^ (lane >> 3);
        floatx4* dst = (floatx4*)(out + (size_t)v * 8192u
                                      + (unsigned)w * 2048u + (unsigned)lane * 4u);
        #pragma unroll
        for (int jj = 0; jj < 8; ++jj) {
            const int m = w * 64 + jj * 8 + (lane >> 3);
            __builtin_nontemporal_store(st[m * 8 + x], dst + jj * 64);
        }
    }
}

// ======================= legacy fallback chain (R4-verified) =================
__global__ __launch_bounds__(1024) void k_levels(
    const float* __restrict__ inLb,
    const float* __restrict__ inRb,
    const float* __restrict__ treeL,
    const float* __restrict__ treeR,
    const float* __restrict__ treeLb,
    const float* __restrict__ treeRb,
    const float* __restrict__ outLs,
    const float* __restrict__ outB,
    float* __restrict__ ws)
{
    const int tid = threadIdx.x;
    float* base  = ws + P0;
    float* outLf = ws + P0 + 32;
    float* tLf   = ws + P0 + 1376;
    float* tRf   = ws + P0 + 1460;
    float* tLbf  = ws + P0 + 1544;
    float* tRbf  = ws + P0 + 1586;
    const float* dots = ws + P0 + 1664;
    float* C7    = ws + P0 + 2048;

    for (int i = tid; i < 21 * 64; i += 1024) outLf[i] = outLs[i];
    if (tid < 84)                      tLf[tid]        = treeL[tid];
    else if (tid < 168)                tRf[tid - 84]   = treeR[tid - 84];
    else if (tid < 210)                tLbf[tid - 168] = treeLb[tid - 168];
    else if (tid < 252)                tRbf[tid - 210] = treeRb[tid - 210];
    if (tid < 32) base[tid] = dots[4 + tid] + outB[tid];
    if (tid < 2) {
        ws[tid * 2 + 0] = dots[tid]     + inLb[tid];
        ws[tid * 2 + 1] = dots[2 + tid] + inRb[tid];
    }
    __syncthreads();

    for (int i = 1; i <= 13; ++i) {
        const float* prev = ws + ((1u << (i + 1)) - 4);
        float* cur        = ws + ((1u << (i + 2)) - 4);
        const int rows = 1 << (i + 1);
        const int lowmask = (1 << (i - 1)) - 1;
        for (int m = tid; m < rows; m += 1024) {
            const int src = ((m >> i) << (i - 1)) | (m & lowmask);
            const int s = (m >> (i - 1)) & 1;
            const float* W  = (s ? tRf  : tLf)  + (i - 1) * 4;
            const float* bb = (s ? tRbf : tLbf) + (i - 1) * 2;
            const float p0 = prev[src * 2], p1 = prev[src * 2 + 1];
            cur[m * 2 + 0] = W[0] * p0 + W[1] * p1 + bb[0];
            cur[m * 2 + 1] = W[2] * p0 + W[3] * p1 + bb[1];
        }
        __syncthreads();
    }

    for (int idx = tid; idx < 8192; idx += 1024) {
        const int m = idx >> 5, o = idx & 31;
        float s = base[o];
        #pragma unroll
        for (int i = 0; i < 8; ++i) {
            const float* ri = ws + ((1u << (i + 2)) - 4) + (m & ((2 << i) - 1)) * 2;
            s += ri[0] * outLf[i * 64 + o * 2] + ri[1] * outLf[i * 64 + o * 2 + 1];
        }
        C7[idx] = s;
    }
}

__global__ __launch_bounds__(256) void k_mid(float* __restrict__ ws)
{
    const int blk = blockIdx.x;
    int j, b;
    if      (blk < 16) { j = 14; b = blk; }
    else if (blk < 48) { j = 15; b = blk - 16; }
    else               { j = 16; b = blk - 48; }

    const float* tLf  = ws + P0 + 1376;
    const float* tRf  = ws + P0 + 1460;
    const float* tLbf = ws + P0 + 1544;
    const float* tRbf = ws + P0 + 1586;

    unsigned m = (unsigned)b << 11;
    const unsigned basej = m;
    unsigned sbits = 0;
    for (int l = j; l > 13; --l) {
        sbits |= ((m >> (l - 1)) & 1u) << l;
        m = ((m >> l) << (l - 1)) | (m & ((1u << (l - 1)) - 1));
    }

    const int r0 = threadIdx.x * 8;
    const floatx4* s4 = (const floatx4*)(ws + ((1u << 15) - 4) + (m + r0) * 2);
    floatx4 a0 = s4[0], a1 = s4[1], a2 = s4[2], a3 = s4[3];
    float r[8][2] = {{a0.x,a0.y},{a0.z,a0.w},{a1.x,a1.y},{a1.z,a1.w},
                     {a2.x,a2.y},{a2.z,a2.w},{a3.x,a3.y},{a3.z,a3.w}};

    for (int l = 14; l <= j; ++l) {
        const int s = (sbits >> l) & 1;
        const float* W  = (s ? tRf  : tLf)  + (l - 1) * 4;
        const float* bb = (s ? tRbf : tLbf) + (l - 1) * 2;
        const float w00 = W[0], w01 = W[1], w10 = W[2], w11 = W[3];
        const float b0 = bb[0], b1 = bb[1];
        #pragma unroll
        for (int q = 0; q < 8; ++q) {
            const float p0 = r[q][0], p1 = r[q][1];
            r[q][0] = w00 * p0 + w01 * p1 + b0;
            r[q][1] = w10 * p0 + w11 * p1 + b1;
        }
    }

    floatx4* d4 = (floatx4*)(ws + ((1u << (j + 2)) - 4) + (basej + r0) * 2);
    d4[0] = (floatx4){r[0][0], r[0][1], r[1][0], r[1][1]};
    d4[1] = (floatx4){r[2][0], r[2][1], r[3][0], r[3][1]};
    d4[2] = (floatx4){r[4][0], r[4][1], r[5][0], r[5][1]};
    d4[3] = (floatx4){r[6][0], r[6][1], r[7][0], r[7][1]};
}

__global__ __launch_bounds__(256) void k_c14(float* __restrict__ ws)
{
    const unsigned m = blockIdx.x * 256u + threadIdx.x;
    const float* outLf = ws + P0 + 32;
    const float* C7    = ws + P0 + 2048;

    float acc[32];
    const floatx4* c4 = (const floatx4*)(C7 + (m & 255u) * 32);
    #pragma unroll
    for (int q = 0; q < 8; ++q) {
        floatx4 v = c4[q];
        acc[q * 4 + 0] = v.x; acc[q * 4 + 1] = v.y;
        acc[q * 4 + 2] = v.z; acc[q * 4 + 3] = v.w;
    }
    #pragma unroll
    for (int i = 8; i <= 14; ++i) {
        const float2 v = *(const float2*)(ws + ((1u << (i + 2)) - 4)
                                             + (m & ((2u << i) - 1)) * 2);
        const float* cf = outLf + i * 64;
        #pragma unroll
        for (int o = 0; o < 32; ++o)
            acc[o] += v.x * cf[o * 2] + v.y * cf[o * 2 + 1];
    }
    floatx4* dst = (floatx4*)(ws + C14OFF + m * 32);
    #pragma unroll
    for (int q = 0; q < 8; ++q)
        dst[q] = (floatx4){acc[q * 4 + 0], acc[q * 4 + 1],
                           acc[q * 4 + 2], acc[q * 4 + 3]};
}

__global__ __launch_bounds__(256) void k_final_fold(const float* __restrict__ ws,
                                                    float* __restrict__ out)
{
    __shared__ floatx4 st[256 * 8];
    const int tid = threadIdx.x;
    const unsigned B = blockIdx.x * 256u + tid;
    const float* outLf = ws + P0 + 32;
    const float* tLf   = ws + P0 + 1376;
    const float* tRf   = ws + P0 + 1460;
    const float* tLbf  = ws + P0 + 1544;
    const float* tRbf  = ws + P0 + 1586;
    const float* C14   = ws + C14OFF;

    float acc[32];
    {
        const floatx4* c4 = (const floatx4*)(C14 + (B & 0x7FFFu) * 32);
        #pragma unroll
        for (int q = 0; q < 8; ++q) {
            floatx4 v = c4[q];
            acc[q * 4 + 0] = v.x; acc[q * 4 + 1] = v.y;
            acc[q * 4 + 2] = v.z; acc[q * 4 + 3] = v.w;
        }
    }
    {
        const float2 v = *(const float2*)(ws + ((1u << 17) - 4)
                                             + (B & 0xFFFFu) * 2);
        const float* cf = outLf + 15 * 64;
        #pragma unroll
        for (int o = 0; o < 32; ++o)
            acc[o] += v.x * cf[o * 2] + v.y * cf[o * 2 + 1];
    }
    {
        const unsigned Blo = B & 0xFFFFu;
        const float* r16 = ws + ((1u << 18) - 4);
        float2 vA = *(const float2*)(r16 + Blo * 2);
        float2 vC = *(const float2*)(r16 + (Blo + 65536u) * 2);
        float A0 = vA.x, A1 = vA.y;
        float c0 = vC.x, c1 = vC.y;
        {
            const int pick = (B >> 16) & 1;
            const float q0 = pick ? c0 : A0, q1 = pick ? c1 : A1;
            const float* cf = outLf + 16 * 64;
            #pragma unroll
            for (int o = 0; o < 32; ++o)
                acc[o] += q0 * cf[o * 2] + q1 * cf[o * 2 + 1];
        }
        #pragma unroll
        for (int l = 17; l <= 20; ++l) {
            const int s = (B >> (l - 1)) & 1;
            const float* WL = tLf + (l - 1) * 4;
            const float* WR = tRf + (l - 1) * 4;
            const float* bL = tLbf + (l - 1) * 2;
            const float* bR = tRbf + (l - 1) * 2;
            const float w00 = s ? WR[0] : WL[0], w01 = s ? WR[1] : WL[1];
            const float w10 = s ? WR[2] : WL[2], w11 = s ? WR[3] : WL[3];
            const float b0  = s ? bR[0] : bL[0], b1  = s ? bR[1] : bL[1];
            const float nA0 = w00 * A0 + w01 * A1 + b0;
            const float nA1 = w10 * A0 + w11 * A1 + b1;
            const float nc0 = w00 * c0 + w01 * c1 + b0;
            const float nc1 = w10 * c0 + w11 * c1 + b1;
            A0 = nA0; A1 = nA1; c0 = nc0; c1 = nc1;
            const int pick = (B >> l) & 1;
            const float q0 = pick ? c0 : A0, q1 = pick ? c1 : A1;
            const float* cf = outLf + l * 64;
            #pragma unroll
            for (int o = 0; o < 32; ++o)
                acc[o] += q0 * cf[o * 2] + q1 * cf[o * 2 + 1];
        }
    }
    #pragma unroll
    for (int q = 0; q < 8; ++q) {
        st[tid * 8 + (q ^ (tid & 7))] =
            (floatx4){acc[q * 4 + 0], acc[q * 4 + 1],
                      acc[q * 4 + 2], acc[q * 4 + 3]};
    }
    __syncthreads();
    {
        const int w = tid >> 6, lane = tid & 63;
        const int x = (lane & 7) ^ (lane >> 3);
        floatx4* dst = (floatx4*)(out + (size_t)blockIdx.x * 8192u
                                      + (unsigned)w * 2048u + (unsigned)lane * 4u);
        #pragma unroll
        for (int j = 0; j < 8; ++j) {
            const int m = w * 64 + j * 8 + (lane >> 3);
            __builtin_nontemporal_store(st[m * 8 + x], dst + j * 64);
        }
    }
}

__global__ __launch_bounds__(256) void k_final_legacy(const float* __restrict__ ws,
                                                      float* __restrict__ out)
{
    __shared__ floatx4 st[256 * 8];
    const int tid = threadIdx.x;
    const unsigned B = blockIdx.x * 256u + tid;
    const float* outLf = ws + P0 + 32;
    const float* tLf   = ws + P0 + 1376;
    const float* tRf   = ws + P0 + 1460;
    const float* tLbf  = ws + P0 + 1544;
    const float* tRbf  = ws + P0 + 1586;
    const float* C7    = ws + P0 + 2048;

    float acc[32];
    {
        const floatx4* c4 = (const floatx4*)(C7 + (B & 255u) * 32);
        #pragma unroll
        for (int q = 0; q < 8; ++q) {
            floatx4 v = c4[q];
            acc[q * 4 + 0] = v.x; acc[q * 4 + 1] = v.y;
            acc[q * 4 + 2] = v.z; acc[q * 4 + 3] = v.w;
        }
    }
    float p[8][2];
    #pragma unroll
    for (int i = 8; i <= 15; ++i) {
        const float2* ri = (const float2*)(ws + ((1u << (i + 2)) - 4)
                                              + (B & ((2u << i) - 1)) * 2);
        float2 v = *ri;
        p[i - 8][0] = v.x;
        p[i - 8][1] = v.y;
    }
    #pragma unroll
    for (int i = 0; i < 8; ++i) {
        const float* cf = outLf + (i + 8) * 64;
        const float q0 = p[i][0], q1 = p[i][1];
        #pragma unroll
        for (int o = 0; o < 32; ++o)
            acc[o] += q0 * cf[o * 2] + q1 * cf[o * 2 + 1];
    }
    {
        const unsigned Blo = B & 0xFFFFu;
        const float* r16 = ws + ((1u << 18) - 4);
        float2 vA = *(const float2*)(r16 + Blo * 2);
        float2 vC = *(const float2*)(r16 + (Blo + 65536u) * 2);
        float A0 = vA.x, A1 = vA.y;
        float c0 = vC.x, c1 = vC.y;
        {
            const int pick = (B >> 16) & 1;
            const float q0 = pick ? c0 : A0, q1 = pick ? c1 : A1;
            const float* cf = outLf + 16 * 64;
            #pragma unroll
            for (int o = 0; o < 32; ++o)
                acc[o] += q0 * cf[o * 2] + q1 * cf[o * 2 + 1];
        }
        #pragma unroll
        for (int l = 17; l <= 20; ++l) {
            const int s = (B >> (l - 1)) & 1;
            const float* WL = tLf + (l - 1) * 4;
            const float* WR = tRf + (l - 1) * 4;
            const float* bL = tLbf + (l - 1) * 2;
            const float* bR = tRbf + (l - 1) * 2;
            const float w00 = s ? WR[0] : WL[0], w01 = s ? WR[1] : WL[1];
            const float w10 = s ? WR[2] : WL[2], w11 = s ? WR[3] : WL[3];
            const float b0  = s ? bR[0] : bL[0], b1  = s ? bR[1] : bL[1];
            const float nA0 = w00 * A0 + w01 * A1 + b0;
            const float nA1 = w10 * A0 + w11 * A1 + b1;
            const float nc0 = w00 * c0 + w01 * c1 + b0;
            const float nc1 = w10 * c0 + w11 * c1 + b1;
            A0 = nA0; A1 = nA1; c0 = nc0; c1 = nc1;
            const int pick = (B >> l) & 1;
            const float q0 = pick ? c0 : A0, q1 = pick ? c1 : A1;
            const float* cf = outLf + l * 64;
            #pragma unroll
            for (int o = 0; o < 32; ++o)
                acc[o] += q0 * cf[o * 2] + q1 * cf[o * 2 + 1];
        }
    }
    #pragma unroll
    for (int q = 0; q < 8; ++q) {
        st[tid * 8 + (q ^ (tid & 7))] =
            (floatx4){acc[q * 4 + 0], acc[q * 4 + 1],
                      acc[q * 4 + 2], acc[q * 4 + 3]};
    }
    __syncthreads();
    {
        const int w = tid >> 6, lane = tid & 63;
        const int x = (lane & 7) ^ (lane >> 3);
        floatx4* dst = (floatx4*)(out + (size_t)blockIdx.x * 8192u
                                      + (unsigned)w * 2048u + (unsigned)lane * 4u);
        #pragma unroll
        for (int j = 0; j < 8; ++j) {
            const int m = w * 64 + j * 8 + (lane >> 3);
            __builtin_nontemporal_store(st[m * 8 + x], dst + j * 64);
        }
    }
}

extern "C" void kernel_launch(void* const* d_in, const int* in_sizes, int n_in,
                              void* d_out, int out_size, void* d_ws, size_t ws_size,
                              hipStream_t stream) {
    const float* x     = (const float*)d_in[0];
    const float* inL   = (const float*)d_in[1];
    const float* inR   = (const float*)d_in[2];
    const float* inLb  = (const float*)d_in[3];
    const float* inRb  = (const float*)d_in[4];
    const float* treeL = (const float*)d_in[5];
    const float* treeR = (const float*)d_in[6];
    const float* treeLb= (const float*)d_in[7];
    const float* treeRb= (const float*)d_in[8];
    const float* outL0 = (const float*)d_in[9];
    const float* outLs = (const float*)d_in[10];
    const float* outB  = (const float*)d_in[11];
    float* ws = (float*)d_ws;
    float* out = (float*)d_out;

    const bool use_c16 = ws_size >= ((size_t)C16OFF + (1u << 22)) * sizeof(float); // 24 MB
    const bool use_c14 = ws_size >= ((size_t)C14OFF + (1u << 20)) * sizeof(float); //  8 MB

    hipLaunchKernelGGL(k_dots, dim3(36), dim3(1024), 0, stream,
                       x, inL, inR, outL0, ws);
    if (use_c16) {
        hipLaunchKernelGGL(k_paths, dim3(1024), dim3(256), 0, stream,
                           treeL, treeR, treeLb, treeRb, inLb, inRb, ws);
        hipLaunchKernelGGL(k_c16f, dim3(512), dim3(256), 0, stream,
                           outLs, outB, ws);
        hipLaunchKernelGGL(k_final_c16, dim3(1u << 13), dim3(256), 0, stream,
                           ws, outLs, treeL, treeR, treeLb, treeRb, out);
    } else {
        hipLaunchKernelGGL(k_levels, dim3(1), dim3(1024), 0, stream,
                           inLb, inRb, treeL, treeR, treeLb, treeRb, outLs, outB, ws);
        hipLaunchKernelGGL(k_mid, dim3(112), dim3(256), 0, stream, ws);
        if (use_c14) {
            hipLaunchKernelGGL(k_c14, dim3(128), dim3(256), 0, stream, ws);
            hipLaunchKernelGGL(k_final_fold, dim3(1u << 13), dim3(256), 0, stream, ws, out);
        } else {
            hipLaunchKernelGGL(k_final_legacy, dim3(1u << 13), dim3(256), 0, stream, ws, out);
        }
    }
}

// Round 7
// 336.679 us; speedup vs baseline: 1.0159x; 1.0159x over previous
//
#include <hip/hip_runtime.h>
#include <hip/hip_bf16.h>

// BinTreeNetwork (ALL TENSORS FP32):
//   out[B, o] = out0[o] + out_bias[o]
//             + sum_{i=0}^{20} res_i[B mod 2^{i+1}, :] . out_layers[i][o, :]
//
// Main path (ws >= 24 MB), 3 dispatches:
//   k_dots:  36 dot products (x . rows of inL/inR/outL0) -> ws dots[36]
//   k_c16x:  per row m of C16 (2^17 rows): computes res_i[m mod 2^{i+1}] for
//            i=0..16 on the fly (descend to seed recording select bits, ascend
//            applying affine 2x2 chains -- identical op order to the old
//            k_paths, so bitwise-identical values), folds them into
//            C16[m][o] = (dots[4+o]+outB[o]) + sum_i res_i . outL[i][o],
//            and writes res_16[m] to the r16 table as a side output.
//   k_final_c16: out[B] = C16[B&0x1FFFF] + register chains 17..20 from the
//            two level-16 ancestor rows (r16[Blo], r16[Blo+65536]).
//            LDS-transposed (XOR-swizzled, conflict-free) -> contiguous
//            1 KiB-per-instruction nontemporal stores, 1.0x write amp.
//
// ws layout (fp32 elements):
//   [0, 2^19-4)  res tables, level i at (1<<(i+2))-4  (main path uses only
//                the level-16 slice at (1<<18)-4; fallback uses all)
//   P0 = 1<<19: +1664 dots[36]
//     (legacy fallback also uses: +0 base, +32 outLf, +1376 tLf, +1460 tRf,
//      +1544 tLbf, +1586 tRbf, +2048 C7)
//   C14OFF = 1<<20 floats: C14 (fallback, ws >= 8 MB)
//   C16OFF = 1<<21 floats: C16 (main, ws >= 24 MB)

#define P0 (1u << 19)
#define C14OFF (1u << 20)
#define C16OFF (1u << 21)

typedef float floatx4 __attribute__((ext_vector_type(4)));

// ---------------- K0: 36 dot products row.x, one block each -----------------
__global__ __launch_bounds__(1024) void k_dots(
    const float* __restrict__ x,
    const float* __restrict__ inL,
    const float* __restrict__ inR,
    const float* __restrict__ outL0,
    float* __restrict__ ws)
{
    __shared__ float red[16];
    const int d = blockIdx.x;
    const int tid = threadIdx.x;
    const float* row =
        (d < 2) ? inL + d * 4096 :
        (d < 4) ? inR + (d - 2) * 4096 :
                  outL0 + (d - 4) * 4096;
    floatx4 a = ((const floatx4*)row)[tid];
    floatx4 b = ((const floatx4*)x)[tid];
    float s = a.x * b.x + a.y * b.y + a.z * b.z + a.w * b.w;
    #pragma unroll
    for (int off = 32; off; off >>= 1) s += __shfl_down(s, off, 64);
    if ((tid & 63) == 0) red[tid >> 6] = s;
    __syncthreads();
    if (tid < 16) {
        float v = red[tid];
        #pragma unroll
        for (int off = 8; off; off >>= 1) v += __shfl_down(v, off, 16);
        if (tid == 0) ws[P0 + 1664 + d] = v;
    }
}

// ---------------- K1 (main): fold into C16 + r16 side output -----------------
__global__ __launch_bounds__(256) void k_c16x(
    const float* __restrict__ treeL,
    const float* __restrict__ treeR,
    const float* __restrict__ treeLb,
    const float* __restrict__ treeRb,
    const float* __restrict__ inLb,
    const float* __restrict__ inRb,
    const float* __restrict__ outLs,
    const float* __restrict__ outB,
    float* __restrict__ ws)
{
    const unsigned m = blockIdx.x * 256u + threadIdx.x;   // 2^17 rows
    const float* dots = ws + P0 + 1664;

    float acc[32];
    #pragma unroll
    for (int o = 0; o < 32; ++o) acc[o] = dots[4 + o] + outB[o];

    float v16_0 = 0.f, v16_1 = 0.f;
    #pragma unroll
    for (int i = 0; i <= 16; ++i) {           // i is compile-time constant
        unsigned mm = m & ((2u << i) - 1u);
        unsigned sbits = 0;
        #pragma unroll
        for (int l = 16; l >= 1; --l) {       // folds to l=i..1 at compile time
            if (l <= i) {
                sbits |= ((mm >> (l - 1)) & 1u) << l;
                mm = ((mm >> l) << (l - 1)) | (mm & ((1u << (l - 1)) - 1u));
            }
        }
        // mm in {0,1}: seed (identical expression to old k_paths)
        float v0 = dots[mm]     + inLb[mm];
        float v1 = dots[2 + mm] + inRb[mm];
        #pragma unroll
        for (int l = 1; l <= 16; ++l) {       // folds to l=1..i
            if (l <= i) {
                const int s = (sbits >> l) & 1;
                const float* W  = (s ? treeR  : treeL)  + (l - 1) * 4;
                const float* bb = (s ? treeRb : treeLb) + (l - 1) * 2;
                const float n0 = W[0] * v0 + W[1] * v1 + bb[0];
                const float n1 = W[2] * v0 + W[3] * v1 + bb[1];
                v0 = n0; v1 = n1;
            }
        }
        const float* cf = outLs + i * 64;
        #pragma unroll
        for (int o = 0; o < 32; ++o)
            acc[o] += v0 * cf[o * 2] + v1 * cf[o * 2 + 1];
        if (i == 16) { v16_0 = v0; v16_1 = v1; }
    }

    // side output: res_16 table row m (bitwise-identical to old k_paths)
    {
        float2 t; t.x = v16_0; t.y = v16_1;
        ((float2*)(ws + ((1u << 18) - 4)))[m] = t;
    }

    floatx4* dst = (floatx4*)(ws + C16OFF + (size_t)m * 32);
    #pragma unroll
    for (int q = 0; q < 8; ++q)
        dst[q] = (floatx4){acc[q * 4 + 0], acc[q * 4 + 1],
                           acc[q * 4 + 2], acc[q * 4 + 3]};
}

// ---------------- K2 (main): final gather-sum (R5-verified structure) --------
// Per leaf: C16 row + register chains 17..20 (~290 FMA/leaf).
// Store path: LDS transpose (XOR-swizzled, conflict-free) -> contiguous
// 1 KiB-per-instruction nontemporal stores, 1.0x write amplification.
__global__ __launch_bounds__(256) void k_final_c16(
    const float* __restrict__ ws,
    const float* __restrict__ outLs,
    const float* __restrict__ treeL,
    const float* __restrict__ treeR,
    const float* __restrict__ treeLb,
    const float* __restrict__ treeRb,
    float* __restrict__ out)
{
    __shared__ floatx4 st[256 * 8];   // 32 KiB
    const int tid = threadIdx.x;
    const unsigned B = blockIdx.x * 256u + tid;
    const float* C16 = ws + C16OFF;

    float acc[32];
    {   // C16 row (contiguous 128 B, 16B-aligned)
        const floatx4* c4 = (const floatx4*)(C16 + (size_t)(B & 0x1FFFFu) * 32);
        #pragma unroll
        for (int q = 0; q < 8; ++q) {
            floatx4 v = c4[q];
            acc[q * 4 + 0] = v.x; acc[q * 4 + 1] = v.y;
            acc[q * 4 + 2] = v.z; acc[q * 4 + 3] = v.w;
        }
    }

    // levels 17..20: two register chains from the two level-16 ancestor rows
    {
        const unsigned Blo = B & 0xFFFFu;
        const float* r16 = ws + ((1u << 18) - 4);
        float2 vA = *(const float2*)(r16 + Blo * 2);
        float2 vC = *(const float2*)(r16 + (Blo + 65536u) * 2);
        float A0 = vA.x, A1 = vA.y;   // MSB=0 chain
        float c0 = vC.x, c1 = vC.y;   // MSB=1 chain
        #pragma unroll
        for (int l = 17; l <= 20; ++l) {
            const int s = (B >> (l - 1)) & 1;
            const float* WL = treeL  + (l - 1) * 4;   // uniform -> scalar loads
            const float* WR = treeR  + (l - 1) * 4;
            const float* bL = treeLb + (l - 1) * 2;
            const float* bR = treeRb + (l - 1) * 2;
            const float w00 = s ? WR[0] : WL[0], w01 = s ? WR[1] : WL[1];
            const float w10 = s ? WR[2] : WL[2], w11 = s ? WR[3] : WL[3];
            const float b0  = s ? bR[0] : bL[0], b1  = s ? bR[1] : bL[1];
            const float nA0 = w00 * A0 + w01 * A1 + b0;
            const float nA1 = w10 * A0 + w11 * A1 + b1;
            const float nc0 = w00 * c0 + w01 * c1 + b0;
            const float nc1 = w10 * c0 + w11 * c1 + b1;
            A0 = nA0; A1 = nA1; c0 = nc0; c1 = nc1;
            const int pick = (B >> l) & 1;
            const float q0 = pick ? c0 : A0, q1 = pick ? c1 : A1;
            const float* cf = outLs + l * 64;
            #pragma unroll
            for (int o = 0; o < 32; ++o)
                acc[o] += q0 * cf[o * 2] + q1 * cf[o * 2 + 1];
        }
    }

    // ---- transpose through LDS, then fully-coalesced 1 KiB/instr nt stores --
    #pragma unroll
    for (int q = 0; q < 8; ++q) {
        st[tid * 8 + (q ^ (tid & 7))] =
            (floatx4){acc[q * 4 + 0], acc[q * 4 + 1],
                      acc[q * 4 + 2], acc[q * 4 + 3]};
    }
    __syncthreads();
    {
        const int w = tid >> 6, lane = tid & 63;
        const int x = (lane & 7) ^ (lane >> 3);
        floatx4* dst = (floatx4*)(out + (size_t)blockIdx.x * 8192u
                                      + (unsigned)w * 2048u + (unsigned)lane * 4u);
        #pragma unroll
        for (int j = 0; j < 8; ++j) {
            const int m = w * 64 + j * 8 + (lane >> 3);
            __builtin_nontemporal_store(st[m * 8 + x], dst + j * 64);
        }
    }
}

// ======================= legacy fallback chain (R4-verified) =================
__global__ __launch_bounds__(1024) void k_levels(
    const float* __restrict__ inLb,
    const float* __restrict__ inRb,
    const float* __restrict__ treeL,
    const float* __restrict__ treeR,
    const float* __restrict__ treeLb,
    const float* __restrict__ treeRb,
    const float* __restrict__ outLs,
    const float* __restrict__ outB,
    float* __restrict__ ws)
{
    const int tid = threadIdx.x;
    float* base  = ws + P0;
    float* outLf = ws + P0 + 32;
    float* tLf   = ws + P0 + 1376;
    float* tRf   = ws + P0 + 1460;
    float* tLbf  = ws + P0 + 1544;
    float* tRbf  = ws + P0 + 1586;
    const float* dots = ws + P0 + 1664;
    float* C7    = ws + P0 + 2048;

    for (int i = tid; i < 21 * 64; i += 1024) outLf[i] = outLs[i];
    if (tid < 84)                      tLf[tid]        = treeL[tid];
    else if (tid < 168)                tRf[tid - 84]   = treeR[tid - 84];
    else if (tid < 210)                tLbf[tid - 168] = treeLb[tid - 168];
    else if (tid < 252)                tRbf[tid - 210] = treeRb[tid - 210];
    if (tid < 32) base[tid] = dots[4 + tid] + outB[tid];
    if (tid < 2) {
        ws[tid * 2 + 0] = dots[tid]     + inLb[tid];
        ws[tid * 2 + 1] = dots[2 + tid] + inRb[tid];
    }
    __syncthreads();

    for (int i = 1; i <= 13; ++i) {
        const float* prev = ws + ((1u << (i + 1)) - 4);
        float* cur        = ws + ((1u << (i + 2)) - 4);
        const int rows = 1 << (i + 1);
        const int lowmask = (1 << (i - 1)) - 1;
        for (int m = tid; m < rows; m += 1024) {
            const int src = ((m >> i) << (i - 1)) | (m & lowmask);
            const int s = (m >> (i - 1)) & 1;
            const float* W  = (s ? tRf  : tLf)  + (i - 1) * 4;
            const float* bb = (s ? tRbf : tLbf) + (i - 1) * 2;
            const float p0 = prev[src * 2], p1 = prev[src * 2 + 1];
            cur[m * 2 + 0] = W[0] * p0 + W[1] * p1 + bb[0];
            cur[m * 2 + 1] = W[2] * p0 + W[3] * p1 + bb[1];
        }
        __syncthreads();
    }

    for (int idx = tid; idx < 8192; idx += 1024) {
        const int m = idx >> 5, o = idx & 31;
        float s = base[o];
        #pragma unroll
        for (int i = 0; i < 8; ++i) {
            const float* ri = ws + ((1u << (i + 2)) - 4) + (m & ((2 << i) - 1)) * 2;
            s += ri[0] * outLf[i * 64 + o * 2] + ri[1] * outLf[i * 64 + o * 2 + 1];
        }
        C7[idx] = s;
    }
}

__global__ __launch_bounds__(256) void k_mid(float* __restrict__ ws)
{
    const int blk = blockIdx.x;
    int j, b;
    if      (blk < 16) { j = 14; b = blk; }
    else if (blk < 48) { j = 15; b = blk - 16; }
    else               { j = 16; b = blk - 48; }

    const float* tLf  = ws + P0 + 1376;
    const float* tRf  = ws + P0 + 1460;
    const float* tLbf = ws + P0 + 1544;
    const float* tRbf = ws + P0 + 1586;

    unsigned m = (unsigned)b << 11;
    const unsigned basej = m;
    unsigned sbits = 0;
    for (int l = j; l > 13; --l) {
        sbits |= ((m >> (l - 1)) & 1u) << l;
        m = ((m >> l) << (l - 1)) | (m & ((1u << (l - 1)) - 1));
    }

    const int r0 = threadIdx.x * 8;
    const floatx4* s4 = (const floatx4*)(ws + ((1u << 15) - 4) + (m + r0) * 2);
    floatx4 a0 = s4[0], a1 = s4[1], a2 = s4[2], a3 = s4[3];
    float r[8][2] = {{a0.x,a0.y},{a0.z,a0.w},{a1.x,a1.y},{a1.z,a1.w},
                     {a2.x,a2.y},{a2.z,a2.w},{a3.x,a3.y},{a3.z,a3.w}};

    for (int l = 14; l <= j; ++l) {
        const int s = (sbits >> l) & 1;
        const float* W  = (s ? tRf  : tLf)  + (l - 1) * 4;
        const float* bb = (s ? tRbf : tLbf) + (l - 1) * 2;
        const float w00 = W[0], w01 = W[1], w10 = W[2], w11 = W[3];
        const float b0 = bb[0], b1 = bb[1];
        #pragma unroll
        for (int q = 0; q < 8; ++q) {
            const float p0 = r[q][0], p1 = r[q][1];
            r[q][0] = w00 * p0 + w01 * p1 + b0;
            r[q][1] = w10 * p0 + w11 * p1 + b1;
        }
    }

    floatx4* d4 = (floatx4*)(ws + ((1u << (j + 2)) - 4) + (basej + r0) * 2);
    d4[0] = (floatx4){r[0][0], r[0][1], r[1][0], r[1][1]};
    d4[1] = (floatx4){r[2][0], r[2][1], r[3][0], r[3][1]};
    d4[2] = (floatx4){r[4][0], r[4][1], r[5][0], r[5][1]};
    d4[3] = (floatx4){r[6][0], r[6][1], r[7][0], r[7][1]};
}

__global__ __launch_bounds__(256) void k_c14(float* __restrict__ ws)
{
    const unsigned m = blockIdx.x * 256u + threadIdx.x;
    const float* outLf = ws + P0 + 32;
    const float* C7    = ws + P0 + 2048;

    float acc[32];
    const floatx4* c4 = (const floatx4*)(C7 + (m & 255u) * 32);
    #pragma unroll
    for (int q = 0; q < 8; ++q) {
        floatx4 v = c4[q];
        acc[q * 4 + 0] = v.x; acc[q * 4 + 1] = v.y;
        acc[q * 4 + 2] = v.z; acc[q * 4 + 3] = v.w;
    }
    #pragma unroll
    for (int i = 8; i <= 14; ++i) {
        const float2 v = *(const float2*)(ws + ((1u << (i + 2)) - 4)
                                             + (m & ((2u << i) - 1)) * 2);
        const float* cf = outLf + i * 64;
        #pragma unroll
        for (int o = 0; o < 32; ++o)
            acc[o] += v.x * cf[o * 2] + v.y * cf[o * 2 + 1];
    }
    floatx4* dst = (floatx4*)(ws + C14OFF + m * 32);
    #pragma unroll
    for (int q = 0; q < 8; ++q)
        dst[q] = (floatx4){acc[q * 4 + 0], acc[q * 4 + 1],
                           acc[q * 4 + 2], acc[q * 4 + 3]};
}

__global__ __launch_bounds__(256) void k_final_fold(const float* __restrict__ ws,
                                                    float* __restrict__ out)
{
    __shared__ floatx4 st[256 * 8];
    const int tid = threadIdx.x;
    const unsigned B = blockIdx.x * 256u + tid;
    const float* outLf = ws + P0 + 32;
    const float* tLf   = ws + P0 + 1376;
    const float* tRf   = ws + P0 + 1460;
    const float* tLbf  = ws + P0 + 1544;
    const float* tRbf  = ws + P0 + 1586;
    const float* C14   = ws + C14OFF;

    float acc[32];
    {
        const floatx4* c4 = (const floatx4*)(C14 + (B & 0x7FFFu) * 32);
        #pragma unroll
        for (int q = 0; q < 8; ++q) {
            floatx4 v = c4[q];
            acc[q * 4 + 0] = v.x; acc[q * 4 + 1] = v.y;
            acc[q * 4 + 2] = v.z; acc[q * 4 + 3] = v.w;
        }
    }
    {
        const float2 v = *(const float2*)(ws + ((1u << 17) - 4)
                                             + (B & 0xFFFFu) * 2);
        const float* cf = outLf + 15 * 64;
        #pragma unroll
        for (int o = 0; o < 32; ++o)
            acc[o] += v.x * cf[o * 2] + v.y * cf[o * 2 + 1];
    }
    {
        const unsigned Blo = B & 0xFFFFu;
        const float* r16 = ws + ((1u << 18) - 4);
        float2 vA = *(const float2*)(r16 + Blo * 2);
        float2 vC = *(const float2*)(r16 + (Blo + 65536u) * 2);
        float A0 = vA.x, A1 = vA.y;
        float c0 = vC.x, c1 = vC.y;
        {
            const int pick = (B >> 16) & 1;
            const float q0 = pick ? c0 : A0, q1 = pick ? c1 : A1;
            const float* cf = outLf + 16 * 64;
            #pragma unroll
            for (int o = 0; o < 32; ++o)
                acc[o] += q0 * cf[o * 2] + q1 * cf[o * 2 + 1];
        }
        #pragma unroll
        for (int l = 17; l <= 20; ++l) {
            const int s = (B >> (l - 1)) & 1;
            const float* WL = tLf + (l - 1) * 4;
            const float* WR = tRf + (l - 1) * 4;
            const float* bL = tLbf + (l - 1) * 2;
            const float* bR = tRbf + (l - 1) * 2;
            const float w00 = s ? WR[0] : WL[0], w01 = s ? WR[1] : WL[1];
            const float w10 = s ? WR[2] : WL[2], w11 = s ? WR[3] : WL[3];
            const float b0  = s ? bR[0] : bL[0], b1  = s ? bR[1] : bL[1];
            const float nA0 = w00 * A0 + w01 * A1 + b0;
            const float nA1 = w10 * A0 + w11 * A1 + b1;
            const float nc0 = w00 * c0 + w01 * c1 + b0;
            const float nc1 = w10 * c0 + w11 * c1 + b1;
            A0 = nA0; A1 = nA1; c0 = nc0; c1 = nc1;
            const int pick = (B >> l) & 1;
            const float q0 = pick ? c0 : A0, q1 = pick ? c1 : A1;
            const float* cf = outLf + l * 64;
            #pragma unroll
            for (int o = 0; o < 32; ++o)
                acc[o] += q0 * cf[o * 2] + q1 * cf[o * 2 + 1];
        }
    }
    #pragma unroll
    for (int q = 0; q < 8; ++q) {
        st[tid * 8 + (q ^ (tid & 7))] =
            (floatx4){acc[q * 4 + 0], acc[q * 4 + 1],
                      acc[q * 4 + 2], acc[q * 4 + 3]};
    }
    __syncthreads();
    {
        const int w = tid >> 6, lane = tid & 63;
        const int x = (lane & 7) ^ (lane >> 3);
        floatx4* dst = (floatx4*)(out + (size_t)blockIdx.x * 8192u
                                      + (unsigned)w * 2048u + (unsigned)lane * 4u);
        #pragma unroll
        for (int j = 0; j < 8; ++j) {
            const int m = w * 64 + j * 8 + (lane >> 3);
            __builtin_nontemporal_store(st[m * 8 + x], dst + j * 64);
        }
    }
}

__global__ __launch_bounds__(256) void k_final_legacy(const float* __restrict__ ws,
                                                      float* __restrict__ out)
{
    __shared__ floatx4 st[256 * 8];
    const int tid = threadIdx.x;
    const unsigned B = blockIdx.x * 256u + tid;
    const float* outLf = ws + P0 + 32;
    const float* tLf   = ws + P0 + 1376;
    const float* tRf   = ws + P0 + 1460;
    const float* tLbf  = ws + P0 + 1544;
    const float* tRbf  = ws + P0 + 1586;
    const float* C7    = ws + P0 + 2048;

    float acc[32];
    {
        const floatx4* c4 = (const floatx4*)(C7 + (B & 255u) * 32);
        #pragma unroll
        for (int q = 0; q < 8; ++q) {
            floatx4 v = c4[q];
            acc[q * 4 + 0] = v.x; acc[q * 4 + 1] = v.y;
            acc[q * 4 + 2] = v.z; acc[q * 4 + 3] = v.w;
        }
    }
    float p[8][2];
    #pragma unroll
    for (int i = 8; i <= 15; ++i) {
        const float2* ri = (const float2*)(ws + ((1u << (i + 2)) - 4)
                                              + (B & ((2u << i) - 1)) * 2);
        float2 v = *ri;
        p[i - 8][0] = v.x;
        p[i - 8][1] = v.y;
    }
    #pragma unroll
    for (int i = 0; i < 8; ++i) {
        const float* cf = outLf + (i + 8) * 64;
        const float q0 = p[i][0], q1 = p[i][1];
        #pragma unroll
        for (int o = 0; o < 32; ++o)
            acc[o] += q0 * cf[o * 2] + q1 * cf[o * 2 + 1];
    }
    {
        const unsigned Blo = B & 0xFFFFu;
        const float* r16 = ws + ((1u << 18) - 4);
        float2 vA = *(const float2*)(r16 + Blo * 2);
        float2 vC = *(const float2*)(r16 + (Blo + 65536u) * 2);
        float A0 = vA.x, A1 = vA.y;
        float c0 = vC.x, c1 = vC.y;
        {
            const int pick = (B >> 16) & 1;
            const float q0 = pick ? c0 : A0, q1 = pick ? c1 : A1;
            const float* cf = outLf + 16 * 64;
            #pragma unroll
            for (int o = 0; o < 32; ++o)
                acc[o] += q0 * cf[o * 2] + q1 * cf[o * 2 + 1];
        }
        #pragma unroll
        for (int l = 17; l <= 20; ++l) {
            const int s = (B >> (l - 1)) & 1;
            const float* WL = tLf + (l - 1) * 4;
            const float* WR = tRf + (l - 1) * 4;
            const float* bL = tLbf + (l - 1) * 2;
            const float* bR = tRbf + (l - 1) * 2;
            const float w00 = s ? WR[0] : WL[0], w01 = s ? WR[1] : WL[1];
            const float w10 = s ? WR[2] : WL[2], w11 = s ? WR[3] : WL[3];
            const float b0  = s ? bR[0] : bL[0], b1  = s ? bR[1] : bL[1];
            const float nA0 = w00 * A0 + w01 * A1 + b0;
            const float nA1 = w10 * A0 + w11 * A1 + b1;
            const float nc0 = w00 * c0 + w01 * c1 + b0;
            const float nc1 = w10 * c0 + w11 * c1 + b1;
            A0 = nA0; A1 = nA1; c0 = nc0; c1 = nc1;
            const int pick = (B >> l) & 1;
            const float q0 = pick ? c0 : A0, q1 = pick ? c1 : A1;
            const float* cf = outLf + l * 64;
            #pragma unroll
            for (int o = 0; o < 32; ++o)
                acc[o] += q0 * cf[o * 2] + q1 * cf[o * 2 + 1];
        }
    }
    #pragma unroll
    for (int q = 0; q < 8; ++q) {
        st[tid * 8 + (q ^ (tid & 7))] =
            (floatx4){acc[q * 4 + 0], acc[q * 4 + 1],
                      acc[q * 4 + 2], acc[q * 4 + 3]};
    }
    __syncthreads();
    {
        const int w = tid >> 6, lane = tid & 63;
        const int x = (lane & 7) ^ (lane >> 3);
        floatx4* dst = (floatx4*)(out + (size_t)blockIdx.x * 8192u
                                      + (unsigned)w * 2048u + (unsigned)lane * 4u);
        #pragma unroll
        for (int j = 0; j < 8; ++j) {
            const int m = w * 64 + j * 8 + (lane >> 3);
            __builtin_nontemporal_store(st[m * 8 + x], dst + j * 64);
        }
    }
}

extern "C" void kernel_launch(void* const* d_in, const int* in_sizes, int n_in,
                              void* d_out, int out_size, void* d_ws, size_t ws_size,
                              hipStream_t stream) {
    const float* x     = (const float*)d_in[0];
    const float* inL   = (const float*)d_in[1];
    const float* inR   = (const float*)d_in[2];
    const float* inLb  = (const float*)d_in[3];
    const float* inRb  = (const float*)d_in[4];
    const float* treeL = (const float*)d_in[5];
    const float* treeR = (const float*)d_in[6];
    const float* treeLb= (const float*)d_in[7];
    const float* treeRb= (const float*)d_in[8];
    const float* outL0 = (const float*)d_in[9];
    const float* outLs = (const float*)d_in[10];
    const float* outB  = (const float*)d_in[11];
    float* ws = (float*)d_ws;
    float* out = (float*)d_out;

    const bool use_c16 = ws_size >= ((size_t)C16OFF + (1u << 22)) * sizeof(float); // 24 MB
    const bool use_c14 = ws_size >= ((size_t)C14OFF + (1u << 20)) * sizeof(float); //  8 MB

    hipLaunchKernelGGL(k_dots, dim3(36), dim3(1024), 0, stream,
                       x, inL, inR, outL0, ws);
    if (use_c16) {
        hipLaunchKernelGGL(k_c16x, dim3(512), dim3(256), 0, stream,
                           treeL, treeR, treeLb, treeRb, inLb, inRb,
                           outLs, outB, ws);
        hipLaunchKernelGGL(k_final_c16, dim3(1u << 13), dim3(256), 0, stream,
                           ws, outLs, treeL, treeR, treeLb, treeRb, out);
    } else {
        hipLaunchKernelGGL(k_levels, dim3(1), dim3(1024), 0, stream,
                           inLb, inRb, treeL, treeR, treeLb, treeRb, outLs, outB, ws);
        hipLaunchKernelGGL(k_mid, dim3(112), dim3(256), 0, stream, ws);
        if (use_c14) {
            hipLaunchKernelGGL(k_c14, dim3(128), dim3(256), 0, stream, ws);
            hipLaunchKernelGGL(k_final_fold, dim3(1u << 13), dim3(256), 0, stream, ws, out);
        } else {
            hipLaunchKernelGGL(k_final_legacy, dim3(1u << 13), dim3(256), 0, stream, ws, out);
        }
    }
}